// Round 12
// baseline (103.877 us; speedup 1.0000x reference)
//
#include <hip/hip_runtime.h>
#include <hip/hip_bf16.h>

#define TGT   64
#define SRCN  64
#define BATCH 32
#define HID   512
#define ATT   512
#define MROWS (TGT * BATCH)          // 2048 rows per z

typedef __bf16 bf16_t;
typedef __bf16 bf16x8 __attribute__((ext_vector_type(8)));
typedef float  f32x4  __attribute__((ext_vector_type(4)));

// HW transcendentals (round-3 lesson: libm exp2f/__frcp_rn cost 29 us).
__device__ __forceinline__ float fast_exp2(float x) {
#if __has_builtin(__builtin_amdgcn_exp2f)
  return __builtin_amdgcn_exp2f(x);
#else
  float r; asm("v_exp_f32 %0, %1\n\ts_nop 1" : "=v"(r) : "v"(x)); return r;
#endif
}
__device__ __forceinline__ float fast_rcp(float x) {
#if __has_builtin(__builtin_amdgcn_rcpf)
  return __builtin_amdgcn_rcpf(x);
#else
  float r; asm("v_rcp_f32 %0, %1\n\ts_nop 1" : "=v"(r) : "v"(x)); return r;
#endif
}

#define MFMA(a, b, c) __builtin_amdgcn_mfma_f32_16x16x32_bf16((a), (b), (c), 0, 0, 0)

// ---------------------------------------------------------------------------
// proj_gemm v3 — UNCHANGED from R11 (passed, absmax 1.95e-3).
// C layout [z][b][st][a], values pre-scaled by SC = 2*log2(e).
// ---------------------------------------------------------------------------
__global__ __launch_bounds__(256) void proj_gemm(
    const float* __restrict__ h_t, const float* __restrict__ srcp,
    const float* __restrict__ Wa, float* __restrict__ C)
{
  const int z = blockIdx.z;
  const float* __restrict__ A = z ? srcp : h_t;
  const int mbase = blockIdx.x * 64;
  const int nbase = blockIdx.y * 64;

  __shared__ bf16_t Ah[64][72];
  __shared__ bf16_t Al[64][72];
  __shared__ bf16_t Bh[64][72];   // transposed: Bh[n][k]
  __shared__ bf16_t Bl[64][72];

  const int tid  = threadIdx.x;
  const int lane = tid & 63;
  const int wv   = tid >> 6;          // 0..3
  const int wm   = (wv & 1) * 32;
  const int wn   = (wv >> 1) * 32;
  const int l15  = lane & 15;
  const int qd   = lane >> 4;

  const int arow = tid >> 2;
  const int akc  = (tid & 3) * 16;
  const int bn = tid & 63;
  const int bkg = (tid >> 6) * 16;

  const float* Aptr = A + (size_t)(mbase + arow) * HID + akc;
  const float* Bptr = Wa + (size_t)(z * HID + bkg) * ATT + nbase + bn;

  f32x4 acc00 = {0.f, 0.f, 0.f, 0.f};
  f32x4 acc01 = acc00, acc10 = acc00, acc11 = acc00;

  for (int kb = 0; kb < HID; kb += 64) {
    if (kb) __syncthreads();

    float4 a0 = *(const float4*)(Aptr + kb);
    float4 a1 = *(const float4*)(Aptr + kb + 4);
    float4 a2 = *(const float4*)(Aptr + kb + 8);
    float4 a3 = *(const float4*)(Aptr + kb + 12);
    const float* bp = Bptr + (size_t)kb * ATT;
    float bv[16];
#pragma unroll
    for (int j = 0; j < 16; ++j) bv[j] = bp[(size_t)j * ATT];

    {
      float av[16] = {a0.x, a0.y, a0.z, a0.w, a1.x, a1.y, a1.z, a1.w,
                      a2.x, a2.y, a2.z, a2.w, a3.x, a3.y, a3.z, a3.w};
      bf16x8 hi0, hi1, lo0, lo1;
#pragma unroll
      for (int j = 0; j < 8; ++j) {
        bf16_t h = (bf16_t)av[j];
        hi0[j] = h;
        lo0[j] = (bf16_t)(av[j] - (float)h);
        bf16_t h2 = (bf16_t)av[j + 8];
        hi1[j] = h2;
        lo1[j] = (bf16_t)(av[j + 8] - (float)h2);
      }
      *(bf16x8*)&Ah[arow][akc]     = hi0;
      *(bf16x8*)&Ah[arow][akc + 8] = hi1;
      *(bf16x8*)&Al[arow][akc]     = lo0;
      *(bf16x8*)&Al[arow][akc + 8] = lo1;
    }
    {
      bf16x8 hi0, hi1, lo0, lo1;
#pragma unroll
      for (int j = 0; j < 8; ++j) {
        bf16_t h = (bf16_t)bv[j];
        hi0[j] = h;
        lo0[j] = (bf16_t)(bv[j] - (float)h);
        bf16_t h2 = (bf16_t)bv[j + 8];
        hi1[j] = h2;
        lo1[j] = (bf16_t)(bv[j + 8] - (float)h2);
      }
      *(bf16x8*)&Bh[bn][bkg]     = hi0;
      *(bf16x8*)&Bh[bn][bkg + 8] = hi1;
      *(bf16x8*)&Bl[bn][bkg]     = lo0;
      *(bf16x8*)&Bl[bn][bkg + 8] = lo1;
    }
    __syncthreads();

#pragma unroll
    for (int h = 0; h < 2; ++h) {
      const int kh = h * 32 + qd * 8;
      bf16x8 ah0 = *(const bf16x8*)&Ah[wm + l15][kh];
      bf16x8 ah1 = *(const bf16x8*)&Ah[wm + 16 + l15][kh];
      bf16x8 al0 = *(const bf16x8*)&Al[wm + l15][kh];
      bf16x8 al1 = *(const bf16x8*)&Al[wm + 16 + l15][kh];
      bf16x8 bh0 = *(const bf16x8*)&Bh[wn + l15][kh];
      bf16x8 bh1 = *(const bf16x8*)&Bh[wn + 16 + l15][kh];
      bf16x8 bl0 = *(const bf16x8*)&Bl[wn + l15][kh];
      bf16x8 bl1 = *(const bf16x8*)&Bl[wn + 16 + l15][kh];

      acc00 = MFMA(ah0, bh0, acc00);
      acc01 = MFMA(ah0, bh1, acc01);
      acc10 = MFMA(ah1, bh0, acc10);
      acc11 = MFMA(ah1, bh1, acc11);
      acc00 = MFMA(al0, bh0, acc00);
      acc01 = MFMA(al0, bh1, acc01);
      acc10 = MFMA(al1, bh0, acc10);
      acc11 = MFMA(al1, bh1, acc11);
      acc00 = MFMA(ah0, bl0, acc00);
      acc01 = MFMA(ah0, bl1, acc01);
      acc10 = MFMA(ah1, bl0, acc10);
      acc11 = MFMA(ah1, bl1, acc11);
    }
  }

  // store to [z][b][st][a] with SC prescale
  const float SC = 2.8853900817779268f;   // 2*log2(e)
  float* Cz = C + (size_t)z * (MROWS * ATT);
#pragma unroll
  for (int r = 0; r < 4; ++r) {
    int m0 = mbase + wm + qd * 4 + r;
    int m1 = m0 + 16;
    int row0 = (m0 & 31) * 64 + (m0 >> 5);
    int row1 = (m1 & 31) * 64 + (m1 >> 5);
    int col0 = nbase + wn + l15;
    Cz[(size_t)row0 * ATT + col0]      = acc00[r] * SC;
    Cz[(size_t)row0 * ATT + col0 + 16] = acc01[r] * SC;
    Cz[(size_t)row1 * ATT + col0]      = acc10[r] * SC;
    Cz[(size_t)row1 * ATT + col0 + 16] = acc11[r] * SC;
  }
}

// ---------------------------------------------------------------------------
// attn_fused v7: lane = s, ZERO cross-lane reduction in the hot loop.
// Wave w owns a in [w*64,(w+1)*64); Es transposed to wave-private LDS via
// coalesced reads + exp2; EHs[a][t] staged once (broadcast reads). Hot loop:
// 8 y-fma + 4 paired-rcp + 8 mul + 8 fma per (a, 64s, 8t). One cross-wave
// partial reduce at the end; softmax in-lane (t=wv); context via attnT[s][t]
// broadcast b128 reads. b = bid>>3 (chunk-dispatch XCD grouping, flipped
// from R11's bid&31 which assumed round-robin).
// ---------------------------------------------------------------------------
__global__ __launch_bounds__(512) void attn_fused(
    const float* __restrict__ ws, const float* __restrict__ srcp,
    const float* __restrict__ Va, float* __restrict__ out)
{
  const float* __restrict__ h_part = ws;                             // [b][t][a], SC-scaled
  const float* __restrict__ s_part = ws + (size_t)TGT * BATCH * ATT; // [b][s][a], SC-scaled

  const int bid  = blockIdx.x;
  const int b    = bid >> 3;          // 8 consecutive bids share b (chunked XCD)
  const int t0   = (bid & 7) * 8;
  const int tid  = threadIdx.x;
  const int lane = tid & 63;
  const int wv   = tid >> 6;          // 0..7

  __shared__ float EHs[512][12];        // [a][t0..7, va@8, pad] 24 KB
  __shared__ float EsW[8][16][65];      // wave-private exp(s_part) chunk, 33.3 KB
  __shared__ float partialQ[8][8][64];  // [w][t][s] 16 KB
  __shared__ float attnT[64][12];       // [s][t] 3 KB
  __shared__ float wsumLds[8];

  // ---- stage EH = exp2(h rows) + Va + vsum ----
  {
    float myva = Va[tid];
    float v = myva;
#pragma unroll
    for (int off = 32; off; off >>= 1) v += __shfl_xor(v, off);
    if (lane == 0) wsumLds[wv] = v;
    EHs[tid][8] = myva;
#pragma unroll
    for (int t = 0; t < 8; ++t) {
      float hv = h_part[(size_t)(b * 64 + t0 + t) * ATT + tid];
      EHs[tid][t] = fast_exp2(hv);
    }
  }
  __syncthreads();

  float vsum = 0.f;
#pragma unroll
  for (int w = 0; w < 8; ++w) vsum += wsumLds[w];

  // ---- scores: wave wv owns a-range [wv*64, wv*64+64), lane = s ----
  float q0 = 0.f, q1 = 0.f, q2 = 0.f, q3 = 0.f;
  float q4 = 0.f, q5 = 0.f, q6 = 0.f, q7 = 0.f;
  const int sstg = lane >> 4;          // staging: s offset 0..3
  const int astg = lane & 15;          // staging: a offset 0..15

  for (int c = 0; c < 4; ++c) {
    const int aBase = wv * 64 + c * 16;
    // stage 16a x 64s wave-private (16 independent loads in flight + exp2)
#pragma unroll
    for (int k = 0; k < 16; ++k) {
      int s = k * 4 + sstg;
      float x = s_part[(size_t)(b * 64 + s) * ATT + aBase + astg];
      EsW[wv][astg][s] = fast_exp2(x);
    }
    // compute (in-wave lgkmcnt ordering; no block barrier needed)
#pragma unroll
    for (int i = 0; i < 16; ++i) {
      float e = EsW[wv][i][lane];
      const int a = aBase + i;
      float4 eh0 = *(const float4*)&EHs[a][0];
      float4 eh1 = *(const float4*)&EHs[a][4];
      float vaa  = EHs[a][8];
      float y0 = fmaf(e, eh0.x, 1.f);
      float y1 = fmaf(e, eh0.y, 1.f);
      float y2 = fmaf(e, eh0.z, 1.f);
      float y3 = fmaf(e, eh0.w, 1.f);
      float y4 = fmaf(e, eh1.x, 1.f);
      float y5 = fmaf(e, eh1.y, 1.f);
      float y6 = fmaf(e, eh1.z, 1.f);
      float y7 = fmaf(e, eh1.w, 1.f);
      float r01 = fast_rcp(y0 * y1);
      float r23 = fast_rcp(y2 * y3);
      float r45 = fast_rcp(y4 * y5);
      float r67 = fast_rcp(y6 * y7);
      q0 = fmaf(vaa * y1, r01, q0);
      q1 = fmaf(vaa * y0, r01, q1);
      q2 = fmaf(vaa * y3, r23, q2);
      q3 = fmaf(vaa * y2, r23, q3);
      q4 = fmaf(vaa * y5, r45, q4);
      q5 = fmaf(vaa * y4, r45, q5);
      q6 = fmaf(vaa * y7, r67, q6);
      q7 = fmaf(vaa * y6, r67, q7);
    }
  }

  // ---- cross-wave partial reduce ----
  partialQ[wv][0][lane] = q0;
  partialQ[wv][1][lane] = q1;
  partialQ[wv][2][lane] = q2;
  partialQ[wv][3][lane] = q3;
  partialQ[wv][4][lane] = q4;
  partialQ[wv][5][lane] = q5;
  partialQ[wv][6][lane] = q6;
  partialQ[wv][7][lane] = q7;
  __syncthreads();

  // thread (t = wv, s = lane) sums 8 partials -> score -> softmax in-lane
  {
    float s_acc = 0.f;
#pragma unroll
    for (int w = 0; w < 8; ++w) s_acc += partialQ[w][wv][lane];
    float score = vsum - 2.f * s_acc;
    float m = score;
#pragma unroll
    for (int off = 32; off; off >>= 1) m = fmaxf(m, __shfl_xor(m, off));
    float e = fast_exp2((score - m) * 1.4426950408889634f);
    float ssum = e;
#pragma unroll
    for (int off = 32; off; off >>= 1) ssum += __shfl_xor(ssum, off);
    attnT[lane][wv] = e * fast_rcp(ssum);
  }
  __syncthreads();

  // ---- context: thread h = tid; attn weights via broadcast b128 reads ----
  {
    float c0 = 0.f, c1 = 0.f, c2 = 0.f, c3 = 0.f;
    float c4 = 0.f, c5 = 0.f, c6 = 0.f, c7 = 0.f;
    const float* sb = srcp + (size_t)b * HID + tid;
#pragma unroll 4
    for (int s = 0; s < SRCN; ++s) {
      float sv = sb[(size_t)s * BATCH * HID];
      float4 a0 = *(const float4*)&attnT[s][0];
      float4 a1 = *(const float4*)&attnT[s][4];
      c0 = fmaf(a0.x, sv, c0);
      c1 = fmaf(a0.y, sv, c1);
      c2 = fmaf(a0.z, sv, c2);
      c3 = fmaf(a0.w, sv, c3);
      c4 = fmaf(a1.x, sv, c4);
      c5 = fmaf(a1.y, sv, c5);
      c6 = fmaf(a1.z, sv, c6);
      c7 = fmaf(a1.w, sv, c7);
    }
    out[((size_t)(t0 + 0) * BATCH + b) * HID + tid] = c0;
    out[((size_t)(t0 + 1) * BATCH + b) * HID + tid] = c1;
    out[((size_t)(t0 + 2) * BATCH + b) * HID + tid] = c2;
    out[((size_t)(t0 + 3) * BATCH + b) * HID + tid] = c3;
    out[((size_t)(t0 + 4) * BATCH + b) * HID + tid] = c4;
    out[((size_t)(t0 + 5) * BATCH + b) * HID + tid] = c5;
    out[((size_t)(t0 + 6) * BATCH + b) * HID + tid] = c6;
    out[((size_t)(t0 + 7) * BATCH + b) * HID + tid] = c7;
  }
}

extern "C" void kernel_launch(void* const* d_in, const int* in_sizes, int n_in,
                              void* d_out, int out_size, void* d_ws, size_t ws_size,
                              hipStream_t stream) {
  const float* h_t = (const float*)d_in[0];   // (64,32,512)
  const float* src = (const float*)d_in[1];   // (64,32,512)
  const float* Wa  = (const float*)d_in[2];   // (1024,512)
  const float* Va  = (const float*)d_in[3];   // (512,)
  float* out = (float*)d_out;                 // (64,32,512)
  float* C   = (float*)d_ws;                  // 8 MB: [z][b][st][a] fp32, SC-prescaled

  proj_gemm<<<dim3(32, 8, 2), 256, 0, stream>>>(h_t, src, Wa, C);
  attn_fused<<<256, 512, 0, stream>>>(C, src, Va, out);
}